// Round 1
// baseline (610.765 us; speedup 1.0000x reference)
//
#include <hip/hip_runtime.h>
#include <hip/hip_bf16.h>
#include <cstdint>

#define N_NOTES 4096
#define SIZE 64
#define NE 14
#define NITER 5
#define MAXDEG 64
#define KTOT 960   /* 15*64 : 14 edge-type act chunks + h chunk */
#define NCOL 192   /* az | ar | ah */

typedef __attribute__((ext_vector_type(8))) short short8;
typedef __attribute__((ext_vector_type(4))) float float4v;

__device__ __forceinline__ ushort f2bf(float f){
  union{float f; uint32_t u;} x; x.f=f;
  uint32_t r = x.u + 0x7fffu + ((x.u>>16)&1u);
  return (ushort)(r>>16);
}
__device__ __forceinline__ float bf2f(ushort h){
  union{uint32_t u; float f;} x; x.u=((uint32_t)h)<<16; return x.f;
}
__device__ __forceinline__ void split_bf(float v, ushort& hi, ushort& lo){
  hi = f2bf(v);
  lo = f2bf(v - bf2f(hi));   // exact residual; hi+lo ~ 16-17 mantissa bits
}

// ---- Pass 1: edge_matrix [14,4096,4096] f32 -> per-(e,n) adjacency (column lists)
__global__ __launch_bounds__(256) void k_build(const float4v* __restrict__ edge4,
                                               int* __restrict__ deg,
                                               ushort* __restrict__ adj){
  int row = blockIdx.x;            // e*4096 + m
  int e = row >> 12, m = row & 4095;
  const float4v* p = edge4 + (size_t)row * (N_NOTES/4);
  int t = threadIdx.x;
  #pragma unroll
  for (int i=0;i<4;i++){
    int idx4 = t + i*256;
    float4v v = p[idx4];
    int nbase = idx4*4;
    #pragma unroll
    for (int j=0;j<4;j++){
      if (v[j] != 0.0f){
        int n = nbase + j;
        int slot = atomicAdd(&deg[(e<<12)+n], 1);
        if (slot < MAXDEG) adj[(size_t)((e<<12)+n)*MAXDEG + slot] = (ushort)m;
      }
    }
  }
}

// ---- Pack weights: Wt[col][k] (transposed, hi/lo bf16). col: g*64+f, k: e*64+d (e==14 -> U)
__global__ __launch_bounds__(256) void k_pack(const float* __restrict__ wz, const float* __restrict__ wr,
                                              const float* __restrict__ wh, const float* __restrict__ uz,
                                              const float* __restrict__ ur, const float* __restrict__ uh,
                                              ushort* __restrict__ WtH, ushort* __restrict__ WtL,
                                              ushort* __restrict__ UtH, ushort* __restrict__ UtL){
  int idx = blockIdx.x*256 + threadIdx.x;
  if (idx < NCOL*KTOT){
    int col = idx / KTOT, k = idx - col*KTOT;
    int e = k >> 6, d = k & 63, g = col >> 6, f = col & 63;
    float v;
    if (e < NE){
      const float* w = (g==0)?wz:(g==1)?wr:wh;
      v = w[(e*64 + d)*64 + f];
    } else {
      v = (g==0) ? uz[d*64+f] : (g==1) ? ur[d*64+f] : 0.0f;  // ah gets no U here ((r*h)@uh later)
    }
    ushort hi,lo; split_bf(v,hi,lo);
    WtH[idx]=hi; WtL[idx]=lo;
  } else {
    int j = idx - NCOL*KTOT;
    if (j < 64*64){
      int f = j >> 6, d = j & 63;
      float v = uh[d*64+f];             // Ut[f][d] = uh[d][f]
      ushort hi,lo; split_bf(v,hi,lo);
      UtH[j]=hi; UtL[j]=lo;
    }
  }
}

__global__ __launch_bounds__(256) void k_init(const float* __restrict__ x, float* __restrict__ h,
                                              ushort* __restrict__ actH, ushort* __restrict__ actL){
  int i = blockIdx.x*256 + threadIdx.x;   // < 262144
  float v = x[i];
  h[i] = v;
  ushort hi,lo; split_bf(v,hi,lo);
  actH[(size_t)NE*N_NOTES*SIZE + i] = hi;
  actL[(size_t)NE*N_NOTES*SIZE + i] = lo;
}

// ---- act[e,n,:] = sum_{m in adj} h[m,:]  (one wave per (e,n), lane = d)
__global__ __launch_bounds__(256) void k_act(const int* __restrict__ deg, const ushort* __restrict__ adj,
                                             const float* __restrict__ h,
                                             ushort* __restrict__ actH, ushort* __restrict__ actL){
  int wid = blockIdx.x*4 + (threadIdx.x >> 6);   // e*4096+n
  int lane = threadIdx.x & 63;
  int dg = deg[wid]; if (dg > MAXDEG) dg = MAXDEG;
  const ushort* a = adj + (size_t)wid*MAXDEG;
  float acc = 0.f;
  for (int k=0;k<dg;k++){
    int m = a[k];
    acc += h[m*64 + lane];
  }
  ushort hi,lo; split_bf(acc,hi,lo);
  actH[(size_t)wid*64 + lane] = hi;
  actL[(size_t)wid*64 + lane] = lo;
}

// ---- G[4096,192] = A'[4096,960] @ Wt^T, split-precision bf16 MFMA (16x16x32)
__global__ __launch_bounds__(256) void k_gemm1(const ushort* __restrict__ AH, const ushort* __restrict__ AL,
                                               const ushort* __restrict__ BH, const ushort* __restrict__ BL,
                                               float* __restrict__ G){
  int wid = blockIdx.x*4 + (threadIdx.x>>6);     // 0..3071
  int tm = wid / 12, tn = wid - tm*12;
  int lane = threadIdx.x & 63;
  int row = tm*16 + (lane & 15);
  int col = tn*16 + (lane & 15);
  int koff = (lane >> 4) * 8;
  float4v acc = {0.f,0.f,0.f,0.f};
  #pragma unroll 2
  for (int kk=0; kk<30; kk++){
    int c = kk >> 1;
    int doff = ((kk & 1) << 5) + koff;
    size_t aoff = ((size_t)(c*N_NOTES + row))*64 + doff;
    size_t boff = (size_t)col*KTOT + kk*32 + koff;
    short8 aH = *(const short8*)(AH + aoff);
    short8 aL = *(const short8*)(AL + aoff);
    short8 bH = *(const short8*)(BH + boff);
    short8 bL = *(const short8*)(BL + boff);
    acc = __builtin_amdgcn_mfma_f32_16x16x32_bf16(aH,bH,acc,0,0,0);
    acc = __builtin_amdgcn_mfma_f32_16x16x32_bf16(aH,bL,acc,0,0,0);
    acc = __builtin_amdgcn_mfma_f32_16x16x32_bf16(aL,bH,acc,0,0,0);
  }
  int crow0 = tm*16 + ((lane>>4)<<2);
  #pragma unroll
  for (int j=0;j<4;j++)
    G[(size_t)(crow0+j)*NCOL + col] = acc[j];
}

// ---- z,r gates + r*h (bf16 hi/lo for GEMM2)
__global__ __launch_bounds__(256) void k_zr(const float* __restrict__ G, const float* __restrict__ h,
                                            const float* __restrict__ bz, const float* __restrict__ br,
                                            float* __restrict__ zz, float* __restrict__ rr,
                                            ushort* __restrict__ rhH, ushort* __restrict__ rhL){
  int i = blockIdx.x*256 + threadIdx.x;   // < 262144
  int n = i >> 6, f = i & 63;
  float az = G[(size_t)n*NCOL + f]      + bz[f];
  float ar = G[(size_t)n*NCOL + 64 + f] + br[f];
  float z = 1.f/(1.f + expf(-az));
  float r = 1.f/(1.f + expf(-ar));
  zz[i] = z; rr[i] = r;
  float rh = r*h[i];
  ushort hi,lo; split_bf(rh,hi,lo);
  rhH[i]=hi; rhL[i]=lo;
}

// ---- T = (r*h)@uh fused with h_tilde/h update; writes h, d_out, and h's bf16 chunk
__global__ __launch_bounds__(256) void k_g2fin(const ushort* __restrict__ rhH, const ushort* __restrict__ rhL,
                                               const ushort* __restrict__ UtH, const ushort* __restrict__ UtL,
                                               const float* __restrict__ G, const float* __restrict__ bh,
                                               const float* __restrict__ zz, const float* __restrict__ rr,
                                               float* __restrict__ h, float* __restrict__ out,
                                               ushort* __restrict__ actH, ushort* __restrict__ actL){
  int wid = blockIdx.x*4 + (threadIdx.x>>6);   // 0..1023
  int tm = wid >> 2, tn = wid & 3;
  int lane = threadIdx.x & 63;
  int row = tm*16 + (lane&15);
  int col = tn*16 + (lane&15);
  int koff = (lane>>4)*8;
  float4v acc = {0.f,0.f,0.f,0.f};
  #pragma unroll
  for (int kk=0;kk<2;kk++){
    size_t aoff = (size_t)row*64 + kk*32 + koff;
    size_t boff = (size_t)col*64 + kk*32 + koff;
    short8 aH = *(const short8*)(rhH+aoff);
    short8 aL = *(const short8*)(rhL+aoff);
    short8 bH = *(const short8*)(UtH+boff);
    short8 bL = *(const short8*)(UtL+boff);
    acc = __builtin_amdgcn_mfma_f32_16x16x32_bf16(aH,bH,acc,0,0,0);
    acc = __builtin_amdgcn_mfma_f32_16x16x32_bf16(aH,bL,acc,0,0,0);
    acc = __builtin_amdgcn_mfma_f32_16x16x32_bf16(aL,bH,acc,0,0,0);
  }
  int crow0 = tm*16 + ((lane>>4)<<2);
  float bhc = bh[col];
  #pragma unroll
  for (int j=0;j<4;j++){
    int rrow = crow0 + j;
    size_t idx = (size_t)rrow*64 + col;
    float ht = tanhf(G[(size_t)rrow*NCOL + 128 + col] + acc[j] + bhc);
    float z = zz[idx], r = rr[idx];
    float hn = (1.f - z)*h[idx] + r*ht;
    h[idx] = hn;
    out[idx] = hn;
    ushort hi,lo; split_bf(hn,hi,lo);
    actH[(size_t)NE*N_NOTES*SIZE + idx] = hi;
    actL[(size_t)NE*N_NOTES*SIZE + idx] = lo;
  }
}

extern "C" void kernel_launch(void* const* d_in, const int* in_sizes, int n_in,
                              void* d_out, int out_size, void* d_ws, size_t ws_size,
                              hipStream_t stream) {
  const float* x    = (const float*)d_in[0];
  const float* edge = (const float*)d_in[1];
  const float* wz   = (const float*)d_in[2];
  const float* wr   = (const float*)d_in[3];
  const float* wh   = (const float*)d_in[4];
  const float* uz   = (const float*)d_in[5];
  const float* ur   = (const float*)d_in[6];
  const float* uh   = (const float*)d_in[7];
  const float* bz   = (const float*)d_in[8];
  const float* br   = (const float*)d_in[9];
  const float* bh   = (const float*)d_in[10];
  float* out = (float*)d_out;

  char* ws = (char*)d_ws;
  size_t off = 0;
  auto alloc = [&](size_t bytes)->void*{
    void* p = ws + off;
    off = (off + bytes + 255) & ~(size_t)255;
    return p;
  };
  const size_t EN = (size_t)NE * N_NOTES;            // 57344
  const size_t ND = (size_t)N_NOTES * SIZE;          // 262144
  int*    deg  = (int*)   alloc(EN * 4);
  ushort* adj  = (ushort*)alloc(EN * MAXDEG * 2);
  ushort* actH = (ushort*)alloc((NE+1) * ND * 2);
  ushort* actL = (ushort*)alloc((NE+1) * ND * 2);
  ushort* WtH  = (ushort*)alloc((size_t)NCOL * KTOT * 2);
  ushort* WtL  = (ushort*)alloc((size_t)NCOL * KTOT * 2);
  ushort* UtH  = (ushort*)alloc(64*64*2);
  ushort* UtL  = (ushort*)alloc(64*64*2);
  float*  G    = (float*) alloc((size_t)N_NOTES * NCOL * 4);
  float*  zz   = (float*) alloc(ND * 4);
  float*  rrb  = (float*) alloc(ND * 4);
  ushort* rhH  = (ushort*)alloc(ND * 2);
  ushort* rhL  = (ushort*)alloc(ND * 2);
  float*  h    = (float*) alloc(ND * 4);

  hipMemsetAsync(deg, 0, EN * 4, stream);
  k_build<<<NE*N_NOTES, 256, 0, stream>>>((const float4v*)edge, deg, adj);
  k_pack <<<(NCOL*KTOT + 64*64)/256, 256, 0, stream>>>(wz, wr, wh, uz, ur, uh, WtH, WtL, UtH, UtL);
  k_init <<<ND/256, 256, 0, stream>>>(x, h, actH, actL);

  for (int it = 0; it < NITER; ++it){
    k_act  <<<EN/4, 256, 0, stream>>>(deg, adj, h, actH, actL);
    k_gemm1<<<(N_NOTES/16)*(NCOL/16)/4, 256, 0, stream>>>(actH, actL, WtH, WtL, G);
    k_zr   <<<ND/256, 256, 0, stream>>>(G, h, bz, br, zz, rrb, rhH, rhL);
    k_g2fin<<<(N_NOTES/16)*(SIZE/16)/4, 256, 0, stream>>>(rhH, rhL, UtH, UtL, G, bh, zz, rrb, h, out, actH, actL);
  }
}

// Round 2
// 530.748 us; speedup vs baseline: 1.1508x; 1.1508x over previous
//
#include <hip/hip_runtime.h>
#include <hip/hip_bf16.h>
#include <cstdint>

#define N_NOTES 4096
#define SIZE 64
#define NE 14
#define NITER 5
#define MAXDEG 64
#define KTOT 960   /* 15*64 : 14 edge-type act chunks + h chunk */
#define NCOL 192   /* az | ar | ah */
#define GSTRIDE 200

typedef __attribute__((ext_vector_type(8))) short short8;
typedef __attribute__((ext_vector_type(4))) float float4v;

__device__ __forceinline__ ushort f2bf(float f){
  union{float f; uint32_t u;} x; x.f=f;
  uint32_t r = x.u + 0x7fffu + ((x.u>>16)&1u);
  return (ushort)(r>>16);
}
__device__ __forceinline__ float bf2f(ushort h){
  union{uint32_t u; float f;} x; x.u=((uint32_t)h)<<16; return x.f;
}
__device__ __forceinline__ void split_bf(float v, ushort& hi, ushort& lo){
  hi = f2bf(v);
  lo = f2bf(v - bf2f(hi));   // hi+lo ~ 16-17 mantissa bits
}

// ---- Pass 1: edge_matrix [14,4096,4096] f32 -> per-(e,n) adjacency (column lists)
__global__ __launch_bounds__(256) void k_build(const float4v* __restrict__ edge4,
                                               int* __restrict__ deg,
                                               ushort* __restrict__ adj){
  int row = blockIdx.x;            // e*4096 + m
  int e = row >> 12, m = row & 4095;
  const float4v* p = edge4 + (size_t)row * (N_NOTES/4);
  int t = threadIdx.x;
  #pragma unroll
  for (int i=0;i<4;i++){
    int idx4 = t + i*256;
    float4v v = p[idx4];
    int nbase = idx4*4;
    #pragma unroll
    for (int j=0;j<4;j++){
      if (v[j] != 0.0f){
        int n = nbase + j;
        int slot = atomicAdd(&deg[(e<<12)+n], 1);
        if (slot < MAXDEG) adj[(size_t)((e<<12)+n)*MAXDEG + slot] = (ushort)m;
      }
    }
  }
}

// ---- Pack weights: Wt[col][k] (transposed, hi/lo bf16). col: g*64+f, k: e*64+d (e==14 -> U)
__global__ __launch_bounds__(256) void k_pack(const float* __restrict__ wz, const float* __restrict__ wr,
                                              const float* __restrict__ wh, const float* __restrict__ uz,
                                              const float* __restrict__ ur, const float* __restrict__ uh,
                                              ushort* __restrict__ WtH, ushort* __restrict__ WtL,
                                              ushort* __restrict__ UtH, ushort* __restrict__ UtL){
  int idx = blockIdx.x*256 + threadIdx.x;
  if (idx < NCOL*KTOT){
    int col = idx / KTOT, k = idx - col*KTOT;
    int e = k >> 6, d = k & 63, g = col >> 6, f = col & 63;
    float v;
    if (e < NE){
      const float* w = (g==0)?wz:(g==1)?wr:wh;
      v = w[(e*64 + d)*64 + f];
    } else {
      v = (g==0) ? uz[d*64+f] : (g==1) ? ur[d*64+f] : 0.0f;
    }
    ushort hi,lo; split_bf(v,hi,lo);
    WtH[idx]=hi; WtL[idx]=lo;
  } else {
    int j = idx - NCOL*KTOT;
    if (j < 64*64){
      int f = j >> 6, d = j & 63;
      float v = uh[d*64+f];             // Ut[f][d] = uh[d][f]
      ushort hi,lo; split_bf(v,hi,lo);
      UtH[j]=hi; UtL[j]=lo;
    }
  }
}

__global__ __launch_bounds__(256) void k_init(const float* __restrict__ x, float* __restrict__ h,
                                              ushort* __restrict__ actH, ushort* __restrict__ actL){
  int i = blockIdx.x*256 + threadIdx.x;   // < 262144
  float v = x[i];
  h[i] = v;
  ushort hi,lo; split_bf(v,hi,lo);
  actH[(size_t)NE*N_NOTES*SIZE + i] = hi;
  actL[(size_t)NE*N_NOTES*SIZE + i] = lo;
}

// ---- act[e,n,:] = sum_{m in adj} h[m,:]  (one wave per (e,n), lane = d)
//      adjacency row loaded once (2B/lane), indices broadcast via shfl
__global__ __launch_bounds__(256) void k_act(const int* __restrict__ deg, const ushort* __restrict__ adj,
                                             const float* __restrict__ h,
                                             ushort* __restrict__ actH, ushort* __restrict__ actL){
  int wid = blockIdx.x*4 + (threadIdx.x >> 6);   // e*4096+n
  int lane = threadIdx.x & 63;
  int dg = deg[wid]; if (dg > MAXDEG) dg = MAXDEG;
  int mv = adj[(size_t)wid*MAXDEG + lane];       // lane-th slot of this row
  float acc = 0.f;
  for (int k=0;k<dg;k++){
    int m = __shfl(mv, k);
    acc += h[m*64 + lane];
  }
  ushort hi,lo; split_bf(acc,hi,lo);
  actH[(size_t)wid*64 + lane] = hi;
  actL[(size_t)wid*64 + lane] = lo;
}

// ---- Fused per-iteration kernel: GEMM1 -> z/r -> rh -> (rh)@uh -> h update
//      One block per 16 rows; G/z/r/rh live in LDS only; h ping-pong.
__global__ __launch_bounds__(256) void k_iter(const ushort* __restrict__ AH, const ushort* __restrict__ AL,
                                              const ushort* __restrict__ WtH, const ushort* __restrict__ WtL,
                                              const ushort* __restrict__ UtH, const ushort* __restrict__ UtL,
                                              const float* __restrict__ bz, const float* __restrict__ br,
                                              const float* __restrict__ bh,
                                              const float* __restrict__ hin, float* __restrict__ hout,
                                              ushort* __restrict__ actH, ushort* __restrict__ actL,
                                              float* __restrict__ out, int last){
  __shared__ float  Gs[16*GSTRIDE];
  __shared__ float  zS[16*64];
  __shared__ float  rS[16*64];
  __shared__ ushort rhHs[16*64];
  __shared__ ushort rhLs[16*64];

  int w    = threadIdx.x >> 6;
  int lane = threadIdx.x & 63;
  int r0   = blockIdx.x * 16;
  int l15  = lane & 15;
  int koff = (lane >> 4) * 8;
  int row  = r0 + l15;

  // ---- Phase 1: G[16,192] = A'[16,960] @ Wt^T  (wave w -> cols w*48..w*48+47)
  float4v acc[3];
  #pragma unroll
  for (int j=0;j<3;j++) acc[j] = (float4v){0.f,0.f,0.f,0.f};
  int colbase = w*48;
  #pragma unroll 2
  for (int kk=0; kk<30; ++kk){
    int c = kk >> 1;
    int doff = ((kk & 1) << 5) + koff;
    size_t aoff = ((size_t)(c*N_NOTES + row))*64 + doff;
    short8 aH = *(const short8*)(AH + aoff);
    short8 aL = *(const short8*)(AL + aoff);
    #pragma unroll
    for (int j=0;j<3;j++){
      int col = colbase + j*16 + l15;
      size_t boff = (size_t)col*KTOT + kk*32 + koff;
      short8 bH = *(const short8*)(WtH + boff);
      short8 bL = *(const short8*)(WtL + boff);
      acc[j] = __builtin_amdgcn_mfma_f32_16x16x32_bf16(aH,bH,acc[j],0,0,0);
      acc[j] = __builtin_amdgcn_mfma_f32_16x16x32_bf16(aH,bL,acc[j],0,0,0);
      acc[j] = __builtin_amdgcn_mfma_f32_16x16x32_bf16(aL,bH,acc[j],0,0,0);
    }
  }
  {
    int crow0 = (lane>>4)*4;
    #pragma unroll
    for (int j=0;j<3;j++){
      int col = colbase + j*16 + l15;
      #pragma unroll
      for (int i=0;i<4;i++)
        Gs[(crow0+i)*GSTRIDE + col] = acc[j][i];
    }
  }
  __syncthreads();

  // ---- Phase 2: z, r, rh for the 16x64 tile
  {
    int f = threadIdx.x & 63;
    int rbase = threadIdx.x >> 6;        // 0..3
    float bzf = bz[f], brf = br[f];
    #pragma unroll
    for (int jj=0; jj<4; jj++){
      int ri = rbase + jj*4;             // 0..15
      float az = Gs[ri*GSTRIDE + f]      + bzf;
      float ar = Gs[ri*GSTRIDE + 64 + f] + brf;
      float z = 1.f/(1.f + expf(-az));
      float r = 1.f/(1.f + expf(-ar));
      float hv = hin[(size_t)(r0+ri)*64 + f];
      zS[ri*64+f] = z;
      rS[ri*64+f] = r;
      float rh = r*hv;
      ushort hi,lo; split_bf(rh,hi,lo);
      rhHs[ri*64+f] = hi;
      rhLs[ri*64+f] = lo;
    }
  }
  __syncthreads();

  // ---- Phase 3: T = rh[16,64] @ Ut^T  (wave w -> cols w*16..w*16+15)
  int col = w*16 + l15;
  float4v acc2 = {0.f,0.f,0.f,0.f};
  #pragma unroll
  for (int kk=0; kk<2; ++kk){
    const short8 aH = *(const short8*)(rhHs + l15*64 + kk*32 + koff);
    const short8 aL = *(const short8*)(rhLs + l15*64 + kk*32 + koff);
    size_t boff = (size_t)col*64 + kk*32 + koff;
    short8 bH = *(const short8*)(UtH + boff);
    short8 bL = *(const short8*)(UtL + boff);
    acc2 = __builtin_amdgcn_mfma_f32_16x16x32_bf16(aH,bH,acc2,0,0,0);
    acc2 = __builtin_amdgcn_mfma_f32_16x16x32_bf16(aH,bL,acc2,0,0,0);
    acc2 = __builtin_amdgcn_mfma_f32_16x16x32_bf16(aL,bH,acc2,0,0,0);
  }

  // ---- Phase 4: h_tilde, blend, write h_next (+bf16 act slot 14, + out on last)
  {
    int crow0 = (lane>>4)*4;
    float bhc = bh[col];
    #pragma unroll
    for (int j=0;j<4;j++){
      int ri = crow0 + j;
      size_t idx = (size_t)(r0+ri)*64 + col;
      float ht = tanhf(Gs[ri*GSTRIDE + 128 + col] + acc2[j] + bhc);
      float z = zS[ri*64+col], r = rS[ri*64+col];
      float hn = (1.f - z)*hin[idx] + r*ht;
      hout[idx] = hn;
      ushort hi,lo; split_bf(hn,hi,lo);
      actH[(size_t)NE*N_NOTES*SIZE + idx] = hi;
      actL[(size_t)NE*N_NOTES*SIZE + idx] = lo;
      if (last) out[idx] = hn;
    }
  }
}

extern "C" void kernel_launch(void* const* d_in, const int* in_sizes, int n_in,
                              void* d_out, int out_size, void* d_ws, size_t ws_size,
                              hipStream_t stream) {
  const float* x    = (const float*)d_in[0];
  const float* edge = (const float*)d_in[1];
  const float* wz   = (const float*)d_in[2];
  const float* wr   = (const float*)d_in[3];
  const float* wh   = (const float*)d_in[4];
  const float* uz   = (const float*)d_in[5];
  const float* ur   = (const float*)d_in[6];
  const float* uh   = (const float*)d_in[7];
  const float* bz   = (const float*)d_in[8];
  const float* br   = (const float*)d_in[9];
  const float* bh   = (const float*)d_in[10];
  float* out = (float*)d_out;

  char* ws = (char*)d_ws;
  size_t off = 0;
  auto alloc = [&](size_t bytes)->void*{
    void* p = ws + off;
    off = (off + bytes + 255) & ~(size_t)255;
    return p;
  };
  const size_t EN = (size_t)NE * N_NOTES;            // 57344
  const size_t ND = (size_t)N_NOTES * SIZE;          // 262144
  int*    deg  = (int*)   alloc(EN * 4);
  ushort* adj  = (ushort*)alloc(EN * MAXDEG * 2);
  ushort* actH = (ushort*)alloc((NE+1) * ND * 2);
  ushort* actL = (ushort*)alloc((NE+1) * ND * 2);
  ushort* WtH  = (ushort*)alloc((size_t)NCOL * KTOT * 2);
  ushort* WtL  = (ushort*)alloc((size_t)NCOL * KTOT * 2);
  ushort* UtH  = (ushort*)alloc(64*64*2);
  ushort* UtL  = (ushort*)alloc(64*64*2);
  float*  h0   = (float*) alloc(ND * 4);
  float*  h1   = (float*) alloc(ND * 4);

  hipMemsetAsync(deg, 0, EN * 4, stream);
  k_build<<<NE*N_NOTES, 256, 0, stream>>>((const float4v*)edge, deg, adj);
  k_pack <<<(NCOL*KTOT + 64*64)/256, 256, 0, stream>>>(wz, wr, wh, uz, ur, uh, WtH, WtL, UtH, UtL);
  k_init <<<ND/256, 256, 0, stream>>>(x, h0, actH, actL);

  float* hcur = h0;
  float* hnxt = h1;
  for (int it = 0; it < NITER; ++it){
    k_act <<<EN/4, 256, 0, stream>>>(deg, adj, hcur, actH, actL);
    k_iter<<<N_NOTES/16, 256, 0, stream>>>(actH, actL, WtH, WtL, UtH, UtL,
                                           bz, br, bh, hcur, hnxt, actH, actL,
                                           out, (it == NITER-1) ? 1 : 0);
    float* t = hcur; hcur = hnxt; hnxt = t;
  }
}

// Round 3
// 475.339 us; speedup vs baseline: 1.2849x; 1.1166x over previous
//
#include <hip/hip_runtime.h>
#include <hip/hip_bf16.h>
#include <cstdint>

#define N_NOTES 4096
#define SIZE 64
#define NE 14
#define NITER 5
#define MAXDEG 64
#define KTOT 960   /* 15*64 : 14 edge-type act chunks + h chunk */
#define ASTR 968   /* padded LDS k-stride (ushorts); 1936B rows, 16B-aligned */

typedef __attribute__((ext_vector_type(8))) short short8;
typedef __attribute__((ext_vector_type(4))) float float4v;

__device__ __forceinline__ ushort f2bf(float f){
  union{float f; uint32_t u;} x; x.f=f;
  uint32_t r = x.u + 0x7fffu + ((x.u>>16)&1u);
  return (ushort)(r>>16);
}
__device__ __forceinline__ float bf2f(ushort h){
  union{uint32_t u; float f;} x; x.u=((uint32_t)h)<<16; return x.f;
}
__device__ __forceinline__ void split_bf(float v, ushort& hi, ushort& lo){
  hi = f2bf(v);
  lo = f2bf(v - bf2f(hi));   // hi+lo ~ 16-17 mantissa bits
}

// ---- Pass 1: edge_matrix [14,4096,4096] f32 -> per-(e,n) adjacency (column lists)
__global__ __launch_bounds__(256) void k_build(const float4v* __restrict__ edge4,
                                               int* __restrict__ deg,
                                               ushort* __restrict__ adj){
  int row = blockIdx.x;            // e*4096 + m
  int e = row >> 12, m = row & 4095;
  const float4v* p = edge4 + (size_t)row * (N_NOTES/4);
  int t = threadIdx.x;
  #pragma unroll
  for (int i=0;i<4;i++){
    int idx4 = t + i*256;
    float4v v = p[idx4];
    int nbase = idx4*4;
    #pragma unroll
    for (int j=0;j<4;j++){
      if (v[j] != 0.0f){
        int n = nbase + j;
        int slot = atomicAdd(&deg[(e<<12)+n], 1);
        if (slot < MAXDEG) adj[(size_t)((e<<12)+n)*MAXDEG + slot] = (ushort)m;
      }
    }
  }
}

// ---- Pack weights: Wt[col][k] (transposed, hi/lo bf16). col: g*64+f, k: e*64+d (e==14 -> U)
__global__ __launch_bounds__(256) void k_pack(const float* __restrict__ wz, const float* __restrict__ wr,
                                              const float* __restrict__ wh, const float* __restrict__ uz,
                                              const float* __restrict__ ur, const float* __restrict__ uh,
                                              ushort* __restrict__ WtH, ushort* __restrict__ WtL,
                                              ushort* __restrict__ UtH, ushort* __restrict__ UtL){
  int idx = blockIdx.x*256 + threadIdx.x;
  if (idx < NE*64*64*3 + 0 || true) {}
  if (idx < 192*KTOT){
    int col = idx / KTOT, k = idx - col*KTOT;
    int e = k >> 6, d = k & 63, g = col >> 6, f = col & 63;
    float v;
    if (e < NE){
      const float* w = (g==0)?wz:(g==1)?wr:wh;
      v = w[(e*64 + d)*64 + f];
    } else {
      v = (g==0) ? uz[d*64+f] : (g==1) ? ur[d*64+f] : 0.0f;  // ah slot-14 zero ((r*h)@uh later)
    }
    ushort hi,lo; split_bf(v,hi,lo);
    WtH[idx]=hi; WtL[idx]=lo;
  } else {
    int j = idx - 192*KTOT;
    if (j < 64*64){
      int f = j >> 6, d = j & 63;
      float v = uh[d*64+f];             // Ut[f][d] = uh[d][f]
      ushort hi,lo; split_bf(v,hi,lo);
      UtH[j]=hi; UtL[j]=lo;
    }
  }
}

// ---- Fully fused iteration: gather-act(LDS) -> GEMM1(regs) -> rh -> (rh)@uh -> update
//      One block per 16 rows of h. 4 waves. LDS = 62KB (A tile hi/lo; rh recycled into A).
__global__ __launch_bounds__(256) void k_fused(const int* __restrict__ deg, const ushort* __restrict__ adj,
                                               const ushort* __restrict__ WtH, const ushort* __restrict__ WtL,
                                               const ushort* __restrict__ UtH, const ushort* __restrict__ UtL,
                                               const float* __restrict__ bz, const float* __restrict__ br,
                                               const float* __restrict__ bh,
                                               const float* __restrict__ hin, float* __restrict__ hout,
                                               float* __restrict__ out, int last){
  __shared__ ushort aHs[16*ASTR];
  __shared__ ushort aLs[16*ASTR];

  const int tid  = threadIdx.x;
  const int w    = tid >> 6;
  const int lane = tid & 63;
  const int qi   = lane >> 4;      // quarter within wave
  const int ql   = lane & 15;
  const int r0   = blockIdx.x * 16;
  const float4v* hin4 = (const float4v*)hin;

  // ---------- Phase 0: gather act tile [16][960] (bf16 hi/lo) ----------
  // unit (e, ri) handled by (pass p=e, wave w, quarter qi): ri = w*4+qi
  const int ri = w*4 + qi;
  const int n  = r0 + ri;

  // prefetch all deg + first adj slots (independent loads, all in flight)
  int dgv[NE]; int mvv[NE];
  #pragma unroll
  for (int e=0;e<NE;e++){
    int base = (e<<12) + n;
    dgv[e] = deg[base];
    mvv[e] = adj[(size_t)base*MAXDEG + ql];
  }
  #pragma unroll
  for (int p=0; p<15; ++p){
    float4v acc = {0.f,0.f,0.f,0.f};
    if (p < NE){
      int dg = dgv[p]; if (dg > MAXDEG) dg = MAXDEG;
      int kmax = dg < 16 ? dg : 16;
      for (int k=0;k<kmax;k++){
        int m = __shfl(mvv[p], qi*16 + k);
        acc += hin4[m*16 + ql];
      }
      if (dg > 16){
        int base = (p<<12) + n;
        for (int k=16;k<dg;k++){
          int m = adj[(size_t)base*MAXDEG + k];
          acc += hin4[m*16 + ql];
        }
      }
    } else {
      acc = hin4[n*16 + ql];       // slot 14 = h itself
    }
    ushort h0,h1,h2,h3,l0,l1,l2,l3;
    split_bf(acc[0],h0,l0); split_bf(acc[1],h1,l1);
    split_bf(acc[2],h2,l2); split_bf(acc[3],h3,l3);
    int o = ri*ASTR + p*64 + ql*4;
    *(ushort4*)&aHs[o] = make_ushort4(h0,h1,h2,h3);
    *(ushort4*)&aLs[o] = make_ushort4(l0,l1,l2,l3);
  }
  __syncthreads();

  // ---------- Phase 1: G = A[16,960] @ Wt^T ; wave w owns cols g*64 + w*16+l15 ----------
  const int l15  = lane & 15;
  const int koff = (lane >> 4) * 8;
  const int colf = w*16 + l15;     // f index 0..63
  float4v acc[3];
  #pragma unroll
  for (int g=0;g<3;g++) acc[g] = (float4v){0.f,0.f,0.f,0.f};
  #pragma unroll 2
  for (int kk=0; kk<30; ++kk){
    short8 aH = *(const short8*)&aHs[l15*ASTR + kk*32 + koff];
    short8 aL = *(const short8*)&aLs[l15*ASTR + kk*32 + koff];
    #pragma unroll
    for (int g=0; g<3; ++g){
      int boff = (g*64 + colf)*KTOT + kk*32 + koff;
      short8 bH = *(const short8*)(WtH + boff);
      short8 bL = *(const short8*)(WtL + boff);
      acc[g] = __builtin_amdgcn_mfma_f32_16x16x32_bf16(aH,bH,acc[g],0,0,0);
      acc[g] = __builtin_amdgcn_mfma_f32_16x16x32_bf16(aH,bL,acc[g],0,0,0);
      acc[g] = __builtin_amdgcn_mfma_f32_16x16x32_bf16(aL,bH,acc[g],0,0,0);
    }
  }
  __syncthreads();                 // all A reads done -> recycle A region for rh

  // ---------- Phase 2: r, rh (into recycled LDS) ----------
  ushort* rhH = aHs;               // 16 x 72 (padded)
  ushort* rhL = aHs + 16*72;
  const int crow0 = (lane>>4)*4;
  const float brf = br[colf];
  float hrow[4], rreg[4];
  #pragma unroll
  for (int i=0;i<4;i++){
    float hv = hin[(size_t)(r0+crow0+i)*64 + colf];
    hrow[i] = hv;
    float r = 1.f/(1.f + expf(-(acc[1][i] + brf)));
    rreg[i] = r;
    ushort hi,lo; split_bf(r*hv,hi,lo);
    rhH[(crow0+i)*72 + colf] = hi;
    rhL[(crow0+i)*72 + colf] = lo;
  }
  __syncthreads();

  // ---------- Phase 3: T = rh[16,64] @ Ut^T (cols colf) ----------
  float4v acc2 = {0.f,0.f,0.f,0.f};
  #pragma unroll
  for (int kk=0; kk<2; ++kk){
    short8 aH = *(const short8*)&rhH[l15*72 + kk*32 + koff];
    short8 aL = *(const short8*)&rhL[l15*72 + kk*32 + koff];
    int boff = colf*64 + kk*32 + koff;
    short8 bH = *(const short8*)(UtH + boff);
    short8 bL = *(const short8*)(UtL + boff);
    acc2 = __builtin_amdgcn_mfma_f32_16x16x32_bf16(aH,bH,acc2,0,0,0);
    acc2 = __builtin_amdgcn_mfma_f32_16x16x32_bf16(aH,bL,acc2,0,0,0);
    acc2 = __builtin_amdgcn_mfma_f32_16x16x32_bf16(aL,bH,acc2,0,0,0);
  }

  // ---------- Phase 4: z, h_tilde, blend, write ----------
  const float bzf = bz[colf], bhf = bh[colf];
  #pragma unroll
  for (int i=0;i<4;i++){
    float z  = 1.f/(1.f + expf(-(acc[0][i] + bzf)));
    float ht = tanhf(acc[2][i] + acc2[i] + bhf);
    float hn = (1.f - z)*hrow[i] + rreg[i]*ht;
    size_t idx = (size_t)(r0+crow0+i)*64 + colf;
    hout[idx] = hn;
    if (last) out[idx] = hn;
  }
}

extern "C" void kernel_launch(void* const* d_in, const int* in_sizes, int n_in,
                              void* d_out, int out_size, void* d_ws, size_t ws_size,
                              hipStream_t stream) {
  const float* x    = (const float*)d_in[0];
  const float* edge = (const float*)d_in[1];
  const float* wz   = (const float*)d_in[2];
  const float* wr   = (const float*)d_in[3];
  const float* wh   = (const float*)d_in[4];
  const float* uz   = (const float*)d_in[5];
  const float* ur   = (const float*)d_in[6];
  const float* uh   = (const float*)d_in[7];
  const float* bz   = (const float*)d_in[8];
  const float* br   = (const float*)d_in[9];
  const float* bh   = (const float*)d_in[10];
  float* out = (float*)d_out;

  char* ws = (char*)d_ws;
  size_t off = 0;
  auto alloc = [&](size_t bytes)->void*{
    void* p = ws + off;
    off = (off + bytes + 255) & ~(size_t)255;
    return p;
  };
  const size_t EN = (size_t)NE * N_NOTES;            // 57344
  const size_t ND = (size_t)N_NOTES * SIZE;          // 262144
  int*    deg  = (int*)   alloc(EN * 4);
  ushort* adj  = (ushort*)alloc(EN * MAXDEG * 2);
  ushort* WtH  = (ushort*)alloc((size_t)192 * KTOT * 2);
  ushort* WtL  = (ushort*)alloc((size_t)192 * KTOT * 2);
  ushort* UtH  = (ushort*)alloc(64*64*2);
  ushort* UtL  = (ushort*)alloc(64*64*2);
  float*  h0   = (float*) alloc(ND * 4);
  float*  h1   = (float*) alloc(ND * 4);

  hipMemsetAsync(deg, 0, EN * 4, stream);
  k_build<<<NE*N_NOTES, 256, 0, stream>>>((const float4v*)edge, deg, adj);
  k_pack <<<(192*KTOT + 64*64)/256, 256, 0, stream>>>(wz, wr, wh, uz, ur, uh, WtH, WtL, UtH, UtL);
  hipMemcpyAsync(h0, x, ND*4, hipMemcpyDeviceToDevice, stream);

  float* hcur = h0;
  float* hnxt = h1;
  for (int it = 0; it < NITER; ++it){
    k_fused<<<N_NOTES/16, 256, 0, stream>>>(deg, adj, WtH, WtL, UtH, UtL,
                                            bz, br, bh, hcur, hnxt,
                                            out, (it == NITER-1) ? 1 : 0);
    float* t = hcur; hcur = hnxt; hnxt = t;
  }
}

// Round 4
// 377.706 us; speedup vs baseline: 1.6170x; 1.2585x over previous
//
#include <hip/hip_runtime.h>
#include <hip/hip_bf16.h>
#include <cstdint>

#define N_NOTES 4096
#define SIZE 64
#define NE 14
#define NITER 5
#define MAXDEG 64
#define KTOT 960   /* 15*64 : 14 edge-type act chunks + h chunk */
#define ASTR 968   /* padded LDS k-stride (ushorts) */
#define HPAD 4113  /* h rows incl. zero pad rows 4096..4112 (dummy idx 0x1010=4112) */

typedef __attribute__((ext_vector_type(8))) short short8;
typedef __attribute__((ext_vector_type(4))) float float4v;

__device__ __forceinline__ ushort f2bf(float f){
  union{float f; uint32_t u;} x; x.f=f;
  uint32_t r = x.u + 0x7fffu + ((x.u>>16)&1u);
  return (ushort)(r>>16);
}
__device__ __forceinline__ float bf2f(ushort h){
  union{uint32_t u; float f;} x; x.u=((uint32_t)h)<<16; return x.f;
}
__device__ __forceinline__ void split_bf(float v, ushort& hi, ushort& lo){
  hi = f2bf(v);
  lo = f2bf(v - bf2f(hi));   // hi+lo ~ 16-17 mantissa bits
}

// ---- Pass 1: edge_matrix [14,4096,4096] f32 -> per-(e,n) adjacency (column lists)
__global__ __launch_bounds__(256) void k_build(const float4v* __restrict__ edge4,
                                               int* __restrict__ deg,
                                               ushort* __restrict__ adj){
  int row = blockIdx.x;            // e*4096 + m
  int e = row >> 12, m = row & 4095;
  const float4v* p = edge4 + (size_t)row * (N_NOTES/4);
  int t = threadIdx.x;
  #pragma unroll
  for (int i=0;i<4;i++){
    int idx4 = t + i*256;
    float4v v = p[idx4];
    int nbase = idx4*4;
    #pragma unroll
    for (int j=0;j<4;j++){
      if (v[j] != 0.0f){
        int n = nbase + j;
        int slot = atomicAdd(&deg[(e<<12)+n], 1);
        if (slot < MAXDEG) adj[(size_t)((e<<12)+n)*MAXDEG + slot] = (ushort)m;
      }
    }
  }
}

// ---- Pack weights: Wt[col][k] (transposed, hi/lo bf16). col: g*64+f, k: e*64+d (e==14 -> U)
__global__ __launch_bounds__(256) void k_pack(const float* __restrict__ wz, const float* __restrict__ wr,
                                              const float* __restrict__ wh, const float* __restrict__ uz,
                                              const float* __restrict__ ur, const float* __restrict__ uh,
                                              ushort* __restrict__ WtH, ushort* __restrict__ WtL,
                                              ushort* __restrict__ UtH, ushort* __restrict__ UtL){
  int idx = blockIdx.x*256 + threadIdx.x;
  if (idx < 192*KTOT){
    int col = idx / KTOT, k = idx - col*KTOT;
    int e = k >> 6, d = k & 63, g = col >> 6, f = col & 63;
    float v;
    if (e < NE){
      const float* w = (g==0)?wz:(g==1)?wr:wh;
      v = w[(e*64 + d)*64 + f];
    } else {
      v = (g==0) ? uz[d*64+f] : (g==1) ? ur[d*64+f] : 0.0f;  // ah slot-14 zero ((r*h)@uh later)
    }
    ushort hi,lo; split_bf(v,hi,lo);
    WtH[idx]=hi; WtL[idx]=lo;
  } else {
    int j = idx - 192*KTOT;
    if (j < 64*64){
      int f = j >> 6, d = j & 63;
      float v = uh[d*64+f];             // Ut[f][d] = uh[d][f]
      ushort hi,lo; split_bf(v,hi,lo);
      UtH[j]=hi; UtL[j]=lo;
    }
  }
}

// ---- Fully fused iteration: gather-act(LDS) -> GEMM1(regs) -> rh -> (rh)@uh -> update
__global__ __launch_bounds__(256) void k_fused(const int* __restrict__ deg, const ushort* __restrict__ adj,
                                               const ushort* __restrict__ WtH, const ushort* __restrict__ WtL,
                                               const ushort* __restrict__ UtH, const ushort* __restrict__ UtL,
                                               const float* __restrict__ bz, const float* __restrict__ br,
                                               const float* __restrict__ bh,
                                               const float* __restrict__ hin, float* __restrict__ hout,
                                               float* __restrict__ out, int last){
  __shared__ ushort aHs[16*ASTR];
  __shared__ ushort aLs[16*ASTR];

  const int tid  = threadIdx.x;
  const int w    = tid >> 6;
  const int lane = tid & 63;
  const int qi   = lane >> 4;      // quarter within wave
  const int ql   = lane & 15;
  const int r0   = blockIdx.x * 16;
  const float4v* hin4 = (const float4v*)hin;

  // ---------- Phase 0: gather act tile [16][960] (bf16 hi/lo) ----------
  // unit (e, ri) handled by (pass p=e, wave w, quarter qi): ri = w*4+qi
  const int ri = w*4 + qi;
  const int n  = r0 + ri;

  // prefetch all deg + lane's adj slot (independent loads, all in flight)
  int dgv[NE]; int mvv[NE];
  #pragma unroll
  for (int e=0;e<NE;e++){
    int base = (e<<12) + n;
    dgv[e] = deg[base];
    mvv[e] = adj[(size_t)base*MAXDEG + ql];   // slots >= deg hold dummy 4112 -> zero row
  }
  #pragma unroll
  for (int p=0; p<15; ++p){
    float4v a0={0.f,0.f,0.f,0.f}, a1={0.f,0.f,0.f,0.f};
    float4v a2={0.f,0.f,0.f,0.f}, a3={0.f,0.f,0.f,0.f};
    if (p < NE){
      // fixed 16-slot gather, fully unrolled: all loads independent & in flight
      #pragma unroll
      for (int k=0;k<16;k+=4){
        int m0 = __shfl(mvv[p], qi*16 + k);
        int m1 = __shfl(mvv[p], qi*16 + k+1);
        int m2 = __shfl(mvv[p], qi*16 + k+2);
        int m3 = __shfl(mvv[p], qi*16 + k+3);
        a0 += hin4[m0*16 + ql];
        a1 += hin4[m1*16 + ql];
        a2 += hin4[m2*16 + ql];
        a3 += hin4[m3*16 + ql];
      }
      int dg = dgv[p];
      if (dg > 16){                 // rare (~0.4% of units)
        size_t base = (size_t)((p<<12)+n)*MAXDEG;
        for (int k=16;k<dg;k++){
          int m = adj[base + k];
          a0 += hin4[m*16 + ql];
        }
      }
    } else {
      a0 = hin4[n*16 + ql];         // slot 14 = h itself
    }
    float4v acc = (a0 + a1) + (a2 + a3);
    ushort h0,h1,h2,h3,l0,l1,l2,l3;
    split_bf(acc[0],h0,l0); split_bf(acc[1],h1,l1);
    split_bf(acc[2],h2,l2); split_bf(acc[3],h3,l3);
    int o = ri*ASTR + p*64 + ql*4;
    *(ushort4*)&aHs[o] = make_ushort4(h0,h1,h2,h3);
    *(ushort4*)&aLs[o] = make_ushort4(l0,l1,l2,l3);
  }
  __syncthreads();

  // ---------- Phase 1: G = A[16,960] @ Wt^T ; wave w owns cols g*64 + w*16+l15 ----------
  const int l15  = lane & 15;
  const int koff = (lane >> 4) * 8;
  const int colf = w*16 + l15;     // f index 0..63
  float4v acc[3];
  #pragma unroll
  for (int g=0;g<3;g++) acc[g] = (float4v){0.f,0.f,0.f,0.f};
  #pragma unroll 3
  for (int kk=0; kk<30; ++kk){
    short8 aH = *(const short8*)&aHs[l15*ASTR + kk*32 + koff];
    short8 aL = *(const short8*)&aLs[l15*ASTR + kk*32 + koff];
    #pragma unroll
    for (int g=0; g<3; ++g){
      int boff = (g*64 + colf)*KTOT + kk*32 + koff;
      short8 bH = *(const short8*)(WtH + boff);
      short8 bL = *(const short8*)(WtL + boff);
      acc[g] = __builtin_amdgcn_mfma_f32_16x16x32_bf16(aH,bH,acc[g],0,0,0);
      acc[g] = __builtin_amdgcn_mfma_f32_16x16x32_bf16(aH,bL,acc[g],0,0,0);
      acc[g] = __builtin_amdgcn_mfma_f32_16x16x32_bf16(aL,bH,acc[g],0,0,0);
    }
  }
  __syncthreads();                 // all A reads done -> recycle A region for rh

  // ---------- Phase 2: r, rh (into recycled LDS) ----------
  ushort* rhH = aHs;               // 16 x 72 (padded)
  ushort* rhL = aHs + 16*72;
  const int crow0 = (lane>>4)*4;
  const float brf = br[colf];
  float hrow[4], rreg[4];
  #pragma unroll
  for (int i=0;i<4;i++){
    float hv = hin[(size_t)(r0+crow0+i)*64 + colf];
    hrow[i] = hv;
    float r = 1.f/(1.f + expf(-(acc[1][i] + brf)));
    rreg[i] = r;
    ushort hi,lo; split_bf(r*hv,hi,lo);
    rhH[(crow0+i)*72 + colf] = hi;
    rhL[(crow0+i)*72 + colf] = lo;
  }
  __syncthreads();

  // ---------- Phase 3: T = rh[16,64] @ Ut^T (cols colf) ----------
  float4v acc2 = {0.f,0.f,0.f,0.f};
  #pragma unroll
  for (int kk=0; kk<2; ++kk){
    short8 aH = *(const short8*)&rhH[l15*72 + kk*32 + koff];
    short8 aL = *(const short8*)&rhL[l15*72 + kk*32 + koff];
    int boff = colf*64 + kk*32 + koff;
    short8 bH = *(const short8*)(UtH + boff);
    short8 bL = *(const short8*)(UtL + boff);
    acc2 = __builtin_amdgcn_mfma_f32_16x16x32_bf16(aH,bH,acc2,0,0,0);
    acc2 = __builtin_amdgcn_mfma_f32_16x16x32_bf16(aH,bL,acc2,0,0,0);
    acc2 = __builtin_amdgcn_mfma_f32_16x16x32_bf16(aL,bH,acc2,0,0,0);
  }

  // ---------- Phase 4: z, h_tilde, blend, write ----------
  const float bzf = bz[colf], bhf = bh[colf];
  #pragma unroll
  for (int i=0;i<4;i++){
    float z  = 1.f/(1.f + expf(-(acc[0][i] + bzf)));
    float ht = tanhf(acc[2][i] + acc2[i] + bhf);
    float hn = (1.f - z)*hrow[i] + rreg[i]*ht;
    size_t idx = (size_t)(r0+crow0+i)*64 + colf;
    hout[idx] = hn;
    if (last) out[idx] = hn;
  }
}

extern "C" void kernel_launch(void* const* d_in, const int* in_sizes, int n_in,
                              void* d_out, int out_size, void* d_ws, size_t ws_size,
                              hipStream_t stream) {
  const float* x    = (const float*)d_in[0];
  const float* edge = (const float*)d_in[1];
  const float* wz   = (const float*)d_in[2];
  const float* wr   = (const float*)d_in[3];
  const float* wh   = (const float*)d_in[4];
  const float* uz   = (const float*)d_in[5];
  const float* ur   = (const float*)d_in[6];
  const float* uh   = (const float*)d_in[7];
  const float* bz   = (const float*)d_in[8];
  const float* br   = (const float*)d_in[9];
  const float* bh   = (const float*)d_in[10];
  float* out = (float*)d_out;

  char* ws = (char*)d_ws;
  size_t off = 0;
  auto alloc = [&](size_t bytes)->void*{
    void* p = ws + off;
    off = (off + bytes + 255) & ~(size_t)255;
    return p;
  };
  const size_t EN = (size_t)NE * N_NOTES;            // 57344
  const size_t ND = (size_t)N_NOTES * SIZE;          // 262144
  int*    deg  = (int*)   alloc(EN * 4);
  ushort* adj  = (ushort*)alloc(EN * MAXDEG * 2);
  ushort* WtH  = (ushort*)alloc((size_t)192 * KTOT * 2);
  ushort* WtL  = (ushort*)alloc((size_t)192 * KTOT * 2);
  ushort* UtH  = (ushort*)alloc(64*64*2);
  ushort* UtL  = (ushort*)alloc(64*64*2);
  float*  h0   = (float*) alloc((size_t)HPAD * SIZE * 4);
  float*  h1   = (float*) alloc((size_t)HPAD * SIZE * 4);

  hipMemsetAsync(deg, 0, EN * 4, stream);
  hipMemsetAsync(adj, 0x10, EN * MAXDEG * 2, stream);               // dummy idx 0x1010 = 4112
  hipMemsetAsync(h0 + (size_t)N_NOTES*SIZE, 0, (HPAD-N_NOTES)*SIZE*4, stream);
  hipMemsetAsync(h1 + (size_t)N_NOTES*SIZE, 0, (HPAD-N_NOTES)*SIZE*4, stream);
  k_build<<<NE*N_NOTES, 256, 0, stream>>>((const float4v*)edge, deg, adj);
  k_pack <<<(192*KTOT + 64*64)/256, 256, 0, stream>>>(wz, wr, wh, uz, ur, uh, WtH, WtL, UtH, UtL);
  hipMemcpyAsync(h0, x, ND*4, hipMemcpyDeviceToDevice, stream);

  float* hcur = h0;
  float* hnxt = h1;
  for (int it = 0; it < NITER; ++it){
    k_fused<<<N_NOTES/16, 256, 0, stream>>>(deg, adj, WtH, WtL, UtH, UtL,
                                            bz, br, bh, hcur, hnxt,
                                            out, (it == NITER-1) ? 1 : 0);
    float* t = hcur; hcur = hnxt; hnxt = t;
  }
}

// Round 5
// 326.747 us; speedup vs baseline: 1.8692x; 1.1560x over previous
//
#include <hip/hip_runtime.h>
#include <hip/hip_bf16.h>
#include <cstdint>

#define N_NOTES 4096
#define SIZE 64
#define NE 14
#define NITER 5
#define MAXDEG 64
#define KTOT 960   /* 15*64 : 14 edge-type act chunks + h chunk */
#define ASTR 968   /* padded LDS k-stride (ushorts) */
#define HPAD 4113  /* h rows incl. zero pad rows 4096..4112 (dummy idx 0x1010=4112) */
#define PWN 184320 /* 3*4*30*512 fragment-packed Wt elements */
#define PUN 4096   /* 4*2*512 fragment-packed Ut elements */

typedef __attribute__((ext_vector_type(8))) short short8;
typedef __attribute__((ext_vector_type(4))) float float4v;

__device__ __forceinline__ ushort f2bf(float f){
  union{float f; uint32_t u;} x; x.f=f;
  uint32_t r = x.u + 0x7fffu + ((x.u>>16)&1u);
  return (ushort)(r>>16);
}
__device__ __forceinline__ float bf2f(ushort h){
  union{uint32_t u; float f;} x; x.u=((uint32_t)h)<<16; return x.f;
}
__device__ __forceinline__ void split_bf(float v, ushort& hi, ushort& lo){
  hi = f2bf(v);
  lo = f2bf(v - bf2f(hi));   // hi+lo ~ 16-17 mantissa bits
}

// ---- zero/init workspace (replaces 4 hipMemsetAsync dispatches)
__global__ __launch_bounds__(256) void k_zero(int* __restrict__ deg, uint32_t* __restrict__ adj32,
                                              float* __restrict__ h0pad, float* __restrict__ h1pad){
  int i = blockIdx.x*256 + threadIdx.x;
  if (i < NE*N_NOTES) deg[i] = 0;
  for (int j = i; j < NE*N_NOTES*MAXDEG/2; j += gridDim.x*256)
    adj32[j] = 0x10101010u;                    // two ushorts of 4112 (dummy -> zero row)
  if (i < (HPAD-N_NOTES)*SIZE){ h0pad[i] = 0.f; h1pad[i] = 0.f; }
}

// ---- Pass 1: edge_matrix [14,4096,4096] f32 -> per-(e,n) adjacency (column lists)
__global__ __launch_bounds__(256) void k_build(const float4v* __restrict__ edge4,
                                               int* __restrict__ deg,
                                               ushort* __restrict__ adj){
  int row = blockIdx.x;            // e*4096 + m
  int e = row >> 12, m = row & 4095;
  const float4v* p = edge4 + (size_t)row * (N_NOTES/4);
  int t = threadIdx.x;
  #pragma unroll
  for (int i=0;i<4;i++){
    int idx4 = t + i*256;
    float4v v = p[idx4];
    int nbase = idx4*4;
    #pragma unroll
    for (int j=0;j<4;j++){
      if (v[j] != 0.0f){
        int n = nbase + j;
        int slot = atomicAdd(&deg[(e<<12)+n], 1);
        if (slot < MAXDEG) adj[(size_t)((e<<12)+n)*MAXDEG + slot] = (ushort)m;
      }
    }
  }
}

// ---- Pack weights into MFMA-fragment order (coalesced B loads):
//      PW[((g*4+w)*30+kk)*512 + lane*8 + j] = B[col=g*64+w*16+(lane&15)][k=kk*32+(lane>>4)*8+j]
//      B[col][k]: k=e*64+d; e<14 -> {wz,wr,wh}[e][d][f], e==14 -> {uz,ur,0}[d][f]  (f=col&63)
//      PU[(w*2+kk)*512 + lane*8 + j] = uh[k][col],  col=w*16+(lane&15), k=kk*32+(lane>>4)*8+j
__global__ __launch_bounds__(256) void k_pack(const float* __restrict__ wz, const float* __restrict__ wr,
                                              const float* __restrict__ wh, const float* __restrict__ uz,
                                              const float* __restrict__ ur, const float* __restrict__ uh,
                                              ushort* __restrict__ PWH, ushort* __restrict__ PWL,
                                              ushort* __restrict__ PUH, ushort* __restrict__ PUL){
  int idx = blockIdx.x*256 + threadIdx.x;
  if (idx < PWN){
    int j = idx & 7, lane = (idx>>3)&63, t = idx>>9;   // t = (g*4+w)*30+kk
    int kk = t % 30, wg = t/30; int w = wg & 3, g = wg >> 2;
    int col = g*64 + w*16 + (lane&15);
    int k = kk*32 + ((lane>>4)<<3) + j;
    int e = k >> 6, d = k & 63, f = col & 63;
    float v;
    if (e < NE){
      const float* wp = (g==0)?wz:(g==1)?wr:wh;
      v = wp[(e*64 + d)*64 + f];
    } else {
      v = (g==0) ? uz[d*64+f] : (g==1) ? ur[d*64+f] : 0.0f;
    }
    ushort hi,lo; split_bf(v,hi,lo);
    PWH[idx]=hi; PWL[idx]=lo;
  } else if (idx < PWN + PUN){
    int i2 = idx - PWN;
    int j = i2 & 7, lane = (i2>>3)&63, t = i2>>9;      // t = w*2+kk
    int kk = t & 1, w = t >> 1;
    int col = w*16 + (lane&15);
    int k = kk*32 + ((lane>>4)<<3) + j;
    float v = uh[k*64 + col];
    ushort hi,lo; split_bf(v,hi,lo);
    PUH[i2]=hi; PUL[i2]=lo;
  }
}

// ---- Fully fused iteration: gather-act(LDS) -> GEMM1(regs) -> rh -> (rh)@uh -> update
__global__ __launch_bounds__(256) void k_fused(const int* __restrict__ deg, const ushort* __restrict__ adj,
                                               const ushort* __restrict__ PWH, const ushort* __restrict__ PWL,
                                               const ushort* __restrict__ PUH, const ushort* __restrict__ PUL,
                                               const float* __restrict__ bz, const float* __restrict__ br,
                                               const float* __restrict__ bh,
                                               const float* __restrict__ hin, float* __restrict__ hout,
                                               float* __restrict__ out, int last){
  __shared__ ushort aHs[16*ASTR];
  __shared__ ushort aLs[16*ASTR];

  const int tid  = threadIdx.x;
  const int w    = tid >> 6;
  const int lane = tid & 63;
  const int qi   = lane >> 4;      // quarter within wave
  const int ql   = lane & 15;
  const int r0   = blockIdx.x * 16;
  const float4v* hin4 = (const float4v*)hin;

  // ---------- Phase 0: gather act tile [16][960] (bf16 hi/lo) ----------
  const int ri = w*4 + qi;
  const int n  = r0 + ri;

  int dgv[NE]; int mvv[NE];
  #pragma unroll
  for (int e=0;e<NE;e++){
    int base = (e<<12) + n;
    dgv[e] = deg[base];
    mvv[e] = adj[(size_t)base*MAXDEG + ql];   // slots >= deg hold dummy 4112 -> zero row
  }
  #pragma unroll
  for (int p=0; p<15; ++p){
    float4v a0={0.f,0.f,0.f,0.f}, a1={0.f,0.f,0.f,0.f};
    float4v a2={0.f,0.f,0.f,0.f}, a3={0.f,0.f,0.f,0.f};
    if (p < NE){
      #pragma unroll
      for (int k=0;k<16;k+=4){
        int m0 = __shfl(mvv[p], qi*16 + k);
        int m1 = __shfl(mvv[p], qi*16 + k+1);
        int m2 = __shfl(mvv[p], qi*16 + k+2);
        int m3 = __shfl(mvv[p], qi*16 + k+3);
        a0 += hin4[m0*16 + ql];
        a1 += hin4[m1*16 + ql];
        a2 += hin4[m2*16 + ql];
        a3 += hin4[m3*16 + ql];
      }
      int dg = dgv[p];
      if (dg > 16){                 // rare (~0.4% of units)
        size_t base = (size_t)((p<<12)+n)*MAXDEG;
        for (int k=16;k<dg;k++){
          int m = adj[base + k];
          a0 += hin4[m*16 + ql];
        }
      }
    } else {
      a0 = hin4[n*16 + ql];         // slot 14 = h itself
    }
    float4v acc = (a0 + a1) + (a2 + a3);
    ushort h0,h1,h2,h3,l0,l1,l2,l3;
    split_bf(acc[0],h0,l0); split_bf(acc[1],h1,l1);
    split_bf(acc[2],h2,l2); split_bf(acc[3],h3,l3);
    int o = ri*ASTR + p*64 + ql*4;
    *(ushort4*)&aHs[o] = make_ushort4(h0,h1,h2,h3);
    *(ushort4*)&aLs[o] = make_ushort4(l0,l1,l2,l3);
  }
  __syncthreads();

  // ---------- Phase 1: G = A[16,960] @ B ; wave w owns cols g*64 + w*16 + l15 ----------
  const int l15  = lane & 15;
  const int koff = (lane >> 4) * 8;
  const int colf = w*16 + l15;     // f index 0..63
  float4v acc[3];
  #pragma unroll
  for (int g=0;g<3;g++) acc[g] = (float4v){0.f,0.f,0.f,0.f};
  #pragma unroll 3
  for (int kk=0; kk<30; ++kk){
    short8 aH = *(const short8*)&aHs[l15*ASTR + kk*32 + koff];
    short8 aL = *(const short8*)&aLs[l15*ASTR + kk*32 + koff];
    #pragma unroll
    for (int g=0; g<3; ++g){
      int boff = (((g*4 + w)*30 + kk) << 9) + lane*8;   // fully coalesced 1KB/wave
      short8 bH = *(const short8*)(PWH + boff);
      short8 bL = *(const short8*)(PWL + boff);
      acc[g] = __builtin_amdgcn_mfma_f32_16x16x32_bf16(aH,bH,acc[g],0,0,0);
      acc[g] = __builtin_amdgcn_mfma_f32_16x16x32_bf16(aH,bL,acc[g],0,0,0);
      acc[g] = __builtin_amdgcn_mfma_f32_16x16x32_bf16(aL,bH,acc[g],0,0,0);
    }
  }
  __syncthreads();                 // all A reads done -> recycle A region for rh

  // ---------- Phase 2: r, rh (into recycled LDS) ----------
  ushort* rhH = aHs;               // 16 x 72 (padded)
  ushort* rhL = aHs + 16*72;
  const int crow0 = (lane>>4)*4;
  const float brf = br[colf];
  float hrow[4], rreg[4];
  #pragma unroll
  for (int i=0;i<4;i++){
    float hv = hin[(size_t)(r0+crow0+i)*64 + colf];
    hrow[i] = hv;
    float r = 1.f/(1.f + expf(-(acc[1][i] + brf)));
    rreg[i] = r;
    ushort hi,lo; split_bf(r*hv,hi,lo);
    rhH[(crow0+i)*72 + colf] = hi;
    rhL[(crow0+i)*72 + colf] = lo;
  }
  __syncthreads();

  // ---------- Phase 3: T = rh[16,64] @ Ut (cols colf) ----------
  float4v acc2 = {0.f,0.f,0.f,0.f};
  #pragma unroll
  for (int kk=0; kk<2; ++kk){
    short8 aH = *(const short8*)&rhH[l15*72 + kk*32 + koff];
    short8 aL = *(const short8*)&rhL[l15*72 + kk*32 + koff];
    int boff = (((w<<1) + kk) << 9) + lane*8;
    short8 bH = *(const short8*)(PUH + boff);
    short8 bL = *(const short8*)(PUL + boff);
    acc2 = __builtin_amdgcn_mfma_f32_16x16x32_bf16(aH,bH,acc2,0,0,0);
    acc2 = __builtin_amdgcn_mfma_f32_16x16x32_bf16(aH,bL,acc2,0,0,0);
    acc2 = __builtin_amdgcn_mfma_f32_16x16x32_bf16(aL,bH,acc2,0,0,0);
  }

  // ---------- Phase 4: z, h_tilde, blend, write ----------
  const float bzf = bz[colf], bhf = bh[colf];
  #pragma unroll
  for (int i=0;i<4;i++){
    float z  = 1.f/(1.f + expf(-(acc[0][i] + bzf)));
    float ht = tanhf(acc[2][i] + acc2[i] + bhf);
    float hn = (1.f - z)*hrow[i] + rreg[i]*ht;
    size_t idx = (size_t)(r0+crow0+i)*64 + colf;
    hout[idx] = hn;
    if (last) out[idx] = hn;
  }
}

extern "C" void kernel_launch(void* const* d_in, const int* in_sizes, int n_in,
                              void* d_out, int out_size, void* d_ws, size_t ws_size,
                              hipStream_t stream) {
  const float* x    = (const float*)d_in[0];
  const float* edge = (const float*)d_in[1];
  const float* wz   = (const float*)d_in[2];
  const float* wr   = (const float*)d_in[3];
  const float* wh   = (const float*)d_in[4];
  const float* uz   = (const float*)d_in[5];
  const float* ur   = (const float*)d_in[6];
  const float* uh   = (const float*)d_in[7];
  const float* bz   = (const float*)d_in[8];
  const float* br   = (const float*)d_in[9];
  const float* bh   = (const float*)d_in[10];
  float* out = (float*)d_out;

  char* ws = (char*)d_ws;
  size_t off = 0;
  auto alloc = [&](size_t bytes)->void*{
    void* p = ws + off;
    off = (off + bytes + 255) & ~(size_t)255;
    return p;
  };
  const size_t EN = (size_t)NE * N_NOTES;            // 57344
  const size_t ND = (size_t)N_NOTES * SIZE;          // 262144
  int*    deg  = (int*)   alloc(EN * 4);
  ushort* adj  = (ushort*)alloc(EN * MAXDEG * 2);
  ushort* PWH  = (ushort*)alloc((size_t)PWN * 2);
  ushort* PWL  = (ushort*)alloc((size_t)PWN * 2);
  ushort* PUH  = (ushort*)alloc((size_t)PUN * 2);
  ushort* PUL  = (ushort*)alloc((size_t)PUN * 2);
  float*  h0   = (float*) alloc((size_t)HPAD * SIZE * 4);
  float*  h1   = (float*) alloc((size_t)HPAD * SIZE * 4);

  k_zero <<<2048, 256, 0, stream>>>(deg, (uint32_t*)adj,
                                    h0 + ND, h1 + ND);
  k_build<<<NE*N_NOTES, 256, 0, stream>>>((const float4v*)edge, deg, adj);
  k_pack <<<(PWN + PUN)/256, 256, 0, stream>>>(wz, wr, wh, uz, ur, uh, PWH, PWL, PUH, PUL);
  hipMemcpyAsync(h0, x, ND*4, hipMemcpyDeviceToDevice, stream);

  float* hcur = h0;
  float* hnxt = h1;
  for (int it = 0; it < NITER; ++it){
    k_fused<<<N_NOTES/16, 256, 0, stream>>>(deg, adj, PWH, PWL, PUH, PUL,
                                            bz, br, bh, hcur, hnxt,
                                            out, (it == NITER-1) ? 1 : 0);
    float* t = hcur; hcur = hnxt; hnxt = t;
  }
}

// Round 6
// 285.695 us; speedup vs baseline: 2.1378x; 1.1437x over previous
//
#include <hip/hip_runtime.h>
#include <hip/hip_bf16.h>
#include <cstdint>

#define N_NOTES 4096
#define SIZE 64
#define NE 14
#define NITER 5
#define MAXDEG 64
#define KTOT 960   /* 15*64 : 14 edge-type act chunks + h chunk */
#define ASTR 968   /* padded LDS k-stride (ushorts) */
#define HPAD 4113  /* h rows incl. zero pad rows 4096..4112 (dummy idx 0x1010=4112) */
#define PWN 184320 /* 3*4*30*512 fragment-packed Wt elements */
#define PUN 4096   /* 4*2*512 fragment-packed Ut elements */
#define PSTR 264   /* PS slot stride in f32 (2-way banks) */

typedef __attribute__((ext_vector_type(8))) short short8;
typedef __attribute__((ext_vector_type(4))) float float4v;

__device__ __forceinline__ ushort f2bf(float f){
  union{float f; uint32_t u;} x; x.f=f;
  uint32_t r = x.u + 0x7fffu + ((x.u>>16)&1u);
  return (ushort)(r>>16);
}
__device__ __forceinline__ float bf2f(ushort h){
  union{uint32_t u; float f;} x; x.u=((uint32_t)h)<<16; return x.f;
}
__device__ __forceinline__ void split_bf(float v, ushort& hi, ushort& lo){
  hi = f2bf(v);
  lo = f2bf(v - bf2f(hi));   // hi+lo ~ 16-17 mantissa bits
}

// ---- zero/init workspace
__global__ __launch_bounds__(256) void k_zero(int* __restrict__ deg, uint32_t* __restrict__ adj32,
                                              float* __restrict__ h0pad, float* __restrict__ h1pad){
  int i = blockIdx.x*256 + threadIdx.x;
  if (i < NE*N_NOTES) deg[i] = 0;
  for (int j = i; j < NE*N_NOTES*MAXDEG/2; j += gridDim.x*256)
    adj32[j] = 0x10101010u;                    // two ushorts of 4112 (dummy -> zero row)
  if (i < (HPAD-N_NOTES)*SIZE){ h0pad[i] = 0.f; h1pad[i] = 0.f; }
}

// ---- Pass 1: edge_matrix [14,4096,4096] f32 -> per-(e,n) adjacency (column lists)
__global__ __launch_bounds__(256) void k_build(const float4v* __restrict__ edge4,
                                               int* __restrict__ deg,
                                               ushort* __restrict__ adj){
  int row = blockIdx.x;            // e*4096 + m
  int e = row >> 12, m = row & 4095;
  const float4v* p = edge4 + (size_t)row * (N_NOTES/4);
  int t = threadIdx.x;
  #pragma unroll
  for (int i=0;i<4;i++){
    int idx4 = t + i*256;
    float4v v = p[idx4];
    int nbase = idx4*4;
    #pragma unroll
    for (int j=0;j<4;j++){
      if (v[j] != 0.0f){
        int n = nbase + j;
        int slot = atomicAdd(&deg[(e<<12)+n], 1);
        if (slot < MAXDEG) adj[(size_t)((e<<12)+n)*MAXDEG + slot] = (ushort)m;
      }
    }
  }
}

// ---- Pack weights into MFMA-fragment order (coalesced B loads)
__global__ __launch_bounds__(256) void k_pack(const float* __restrict__ wz, const float* __restrict__ wr,
                                              const float* __restrict__ wh, const float* __restrict__ uz,
                                              const float* __restrict__ ur, const float* __restrict__ uh,
                                              ushort* __restrict__ PWH, ushort* __restrict__ PWL,
                                              ushort* __restrict__ PUH, ushort* __restrict__ PUL){
  int idx = blockIdx.x*256 + threadIdx.x;
  if (idx < PWN){
    int j = idx & 7, lane = (idx>>3)&63, t = idx>>9;   // t = (g*4+cb)*30+kk
    int kk = t % 30, wg = t/30; int cb = wg & 3, g = wg >> 2;
    int col = g*64 + cb*16 + (lane&15);
    int k = kk*32 + ((lane>>4)<<3) + j;
    int e = k >> 6, d = k & 63, f = col & 63;
    float v;
    if (e < NE){
      const float* wp = (g==0)?wz:(g==1)?wr:wh;
      v = wp[(e*64 + d)*64 + f];
    } else {
      v = (g==0) ? uz[d*64+f] : (g==1) ? ur[d*64+f] : 0.0f;
    }
    ushort hi,lo; split_bf(v,hi,lo);
    PWH[idx]=hi; PWL[idx]=lo;
  } else if (idx < PWN + PUN){
    int i2 = idx - PWN;
    int j = i2 & 7, lane = (i2>>3)&63, t = i2>>9;      // t = cb*2+kk
    int kk = t & 1, cb = t >> 1;
    int col = cb*16 + (lane&15);
    int k = kk*32 + ((lane>>4)<<3) + j;
    float v = uh[k*64 + col];
    ushort hi,lo; split_bf(v,hi,lo);
    PUH[i2]=hi; PUL[i2]=lo;
  }
}

// ---- Fully fused iteration, 16 waves/block (4 waves/SIMD):
//      gather-act(LDS) -> split-K GEMM1 -> LDS reduce + gates -> (rh)@uh -> update
__global__ __launch_bounds__(1024, 4)
void k_fused(const int* __restrict__ deg, const ushort* __restrict__ adj,
             const ushort* __restrict__ PWH, const ushort* __restrict__ PWL,
             const ushort* __restrict__ PUH, const ushort* __restrict__ PUL,
             const float* __restrict__ bz, const float* __restrict__ br,
             const float* __restrict__ bh,
             const float* __restrict__ hin, float* __restrict__ hout,
             float* __restrict__ out, int last){
  __shared__ ushort sh[31744];                 // 63488 B
  ushort* aHs = sh;                            // [16][ASTR]
  ushort* aLs = sh + 16*ASTR;
  float*  PSf = (float*)sh;                    // 48 slots * PSTR f32 (50688 B)
  ushort* rhH = sh + 25344;                    // byte 50688, 16*72
  ushort* rhL = sh + 26496;                    // byte 52992
  float*  zSf = (float*)(sh + 27648);          // byte 55296, 1024 f32
  float*  rSf = (float*)(sh + 29696);          // byte 59392, 1024 f32

  const int tid  = threadIdx.x;
  const int w    = tid >> 6;                   // wave 0..15
  const int lane = tid & 63;
  const int qi   = lane >> 4;
  const int ql   = lane & 15;
  const int l15  = lane & 15;
  const int koff = (lane >> 4) * 8;
  const int r0   = blockIdx.x * 16;
  const float4v* hin4 = (const float4v*)hin;

  // ---------- Phase 0: gather act tile [16][960]; unit u = e*16+ri, 4 passes over 64 quarters
  const int Q = w*4 + qi;
  int dgv[4], mvv[4];
  #pragma unroll
  for (int p=0;p<4;p++){
    int u = p*64 + Q;
    int e = u >> 4, n = r0 + (u & 15);
    if (e < NE){
      int base = (e<<12) + n;
      dgv[p] = deg[base];
      mvv[p] = adj[(size_t)base*MAXDEG + ql];  // slots >= deg hold dummy 4112 -> zero row
    } else { dgv[p]=0; mvv[p]=0; }
  }
  #pragma unroll
  for (int p=0;p<4;p++){
    int u = p*64 + Q;
    if (u >= 240) continue;
    int e = u >> 4, ri = u & 15, n = r0 + ri;
    float4v a0={0.f,0.f,0.f,0.f}, a1={0.f,0.f,0.f,0.f};
    float4v a2={0.f,0.f,0.f,0.f}, a3={0.f,0.f,0.f,0.f};
    if (e < NE){
      #pragma unroll
      for (int k=0;k<16;k+=4){
        int m0 = __shfl(mvv[p], qi*16 + k);
        int m1 = __shfl(mvv[p], qi*16 + k+1);
        int m2 = __shfl(mvv[p], qi*16 + k+2);
        int m3 = __shfl(mvv[p], qi*16 + k+3);
        a0 += hin4[m0*16 + ql];
        a1 += hin4[m1*16 + ql];
        a2 += hin4[m2*16 + ql];
        a3 += hin4[m3*16 + ql];
      }
      int dg = dgv[p];
      if (dg > 16){                            // rare tail
        size_t base = (size_t)((e<<12)+n)*MAXDEG;
        for (int k=16;k<dg;k++){
          int m = adj[base + k];
          a0 += hin4[m*16 + ql];
        }
      }
    } else {
      a0 = hin4[n*16 + ql];                    // slot 14 = h itself
    }
    float4v acc = (a0 + a1) + (a2 + a3);
    ushort h0,h1,h2,h3,l0,l1,l2,l3;
    split_bf(acc[0],h0,l0); split_bf(acc[1],h1,l1);
    split_bf(acc[2],h2,l2); split_bf(acc[3],h3,l3);
    int o = ri*ASTR + e*64 + ql*4;
    *(ushort4*)&aHs[o] = make_ushort4(h0,h1,h2,h3);
    *(ushort4*)&aLs[o] = make_ushort4(l0,l1,l2,l3);
  }
  __syncthreads();

  // ---------- Phase 1: split-K GEMM1. wave = (cb = w&3, kq = w>>2); kq covers 8 kk (kq3: 6)
  const int cb = w & 3, kq = w >> 2;
  const int kk0 = kq*8;
  float4v acc[3];
  #pragma unroll
  for (int g=0;g<3;g++) acc[g] = (float4v){0.f,0.f,0.f,0.f};
  #pragma unroll
  for (int kx=0; kx<8; ++kx){
    int kk = kk0 + kx;
    if (kk < 30){
      short8 aH = *(const short8*)&aHs[l15*ASTR + kk*32 + koff];
      short8 aL = *(const short8*)&aLs[l15*ASTR + kk*32 + koff];
      #pragma unroll
      for (int g=0; g<3; ++g){
        int boff = (((g*4 + cb)*30 + kk) << 9) + lane*8;
        short8 bH = *(const short8*)(PWH + boff);
        short8 bL = *(const short8*)(PWL + boff);
        acc[g] = __builtin_amdgcn_mfma_f32_16x16x32_bf16(aH,bH,acc[g],0,0,0);
        acc[g] = __builtin_amdgcn_mfma_f32_16x16x32_bf16(aH,bL,acc[g],0,0,0);
        acc[g] = __builtin_amdgcn_mfma_f32_16x16x32_bf16(aL,bH,acc[g],0,0,0);
      }
    }
  }
  __syncthreads();                 // A reads done -> recycle LDS for PS etc.

  // write partials: PS[(kq*12 + g*4+cb)][row][col]
  {
    int crow0 = (lane>>4)*4;
    #pragma unroll
    for (int g=0;g<3;g++){
      float* slot = PSf + (size_t)(kq*12 + g*4 + cb)*PSTR;
      #pragma unroll
      for (int i=0;i<4;i++)
        slot[(crow0+i)*16 + l15] = acc[g][i];
    }
  }
  __syncthreads();

  // ---------- Phase 2 (all 1024 threads): reduce 4 partials, gates, rh; ah back into PS slot (8+cb2)
  {
    int r = tid >> 6, f = tid & 63;
    int cb2 = f >> 4, c = f & 15;
    float az=0.f, ar=0.f, ah=0.f;
    #pragma unroll
    for (int k=0;k<4;k++){
      az += PSf[(size_t)(k*12 + 0 + cb2)*PSTR + r*16 + c];
      ar += PSf[(size_t)(k*12 + 4 + cb2)*PSTR + r*16 + c];
      ah += PSf[(size_t)(k*12 + 8 + cb2)*PSTR + r*16 + c];
    }
    float z = 1.f/(1.f + expf(-(az + bz[f])));
    float rg = 1.f/(1.f + expf(-(ar + br[f])));
    float hv = hin[(size_t)(r0+r)*64 + f];
    zSf[tid] = z;
    rSf[tid] = rg;
    ushort hi,lo; split_bf(rg*hv,hi,lo);
    rhH[r*72+f] = hi;
    rhL[r*72+f] = lo;
    PSf[(size_t)(8 + cb2)*PSTR + r*16 + c] = ah;   // slot (kq=0,g=2): each slot read/written by this thread only
  }
  __syncthreads();

  // ---------- Phase 3+4 (waves 0..3): T = rh @ Ut, then blend + write
  if (w < 4){
    const int colf = w*16 + l15;
    float4v acc2 = {0.f,0.f,0.f,0.f};
    #pragma unroll
    for (int kk=0; kk<2; ++kk){
      short8 aH = *(const short8*)&rhH[l15*72 + kk*32 + koff];
      short8 aL = *(const short8*)&rhL[l15*72 + kk*32 + koff];
      int boff = (((w<<1) + kk) << 9) + lane*8;
      short8 bH = *(const short8*)(PUH + boff);
      short8 bL = *(const short8*)(PUL + boff);
      acc2 = __builtin_amdgcn_mfma_f32_16x16x32_bf16(aH,bH,acc2,0,0,0);
      acc2 = __builtin_amdgcn_mfma_f32_16x16x32_bf16(aH,bL,acc2,0,0,0);
      acc2 = __builtin_amdgcn_mfma_f32_16x16x32_bf16(aL,bH,acc2,0,0,0);
    }
    const int crow0 = (lane>>4)*4;
    const float bhf = bh[colf];
    #pragma unroll
    for (int i=0;i<4;i++){
      int row = crow0 + i;
      float ah = PSf[(size_t)(8 + w)*PSTR + row*16 + l15];
      float z  = zSf[row*64 + colf];
      float rg = rSf[row*64 + colf];
      float ht = tanhf(ah + acc2[i] + bhf);
      size_t idx = (size_t)(r0+row)*64 + colf;
      float hn = (1.f - z)*hin[idx] + rg*ht;
      hout[idx] = hn;
      if (last) out[idx] = hn;
    }
  }
}

extern "C" void kernel_launch(void* const* d_in, const int* in_sizes, int n_in,
                              void* d_out, int out_size, void* d_ws, size_t ws_size,
                              hipStream_t stream) {
  const float* x    = (const float*)d_in[0];
  const float* edge = (const float*)d_in[1];
  const float* wz   = (const float*)d_in[2];
  const float* wr   = (const float*)d_in[3];
  const float* wh   = (const float*)d_in[4];
  const float* uz   = (const float*)d_in[5];
  const float* ur   = (const float*)d_in[6];
  const float* uh   = (const float*)d_in[7];
  const float* bz   = (const float*)d_in[8];
  const float* br   = (const float*)d_in[9];
  const float* bh   = (const float*)d_in[10];
  float* out = (float*)d_out;

  char* ws = (char*)d_ws;
  size_t off = 0;
  auto alloc = [&](size_t bytes)->void*{
    void* p = ws + off;
    off = (off + bytes + 255) & ~(size_t)255;
    return p;
  };
  const size_t EN = (size_t)NE * N_NOTES;            // 57344
  const size_t ND = (size_t)N_NOTES * SIZE;          // 262144
  int*    deg  = (int*)   alloc(EN * 4);
  ushort* adj  = (ushort*)alloc(EN * MAXDEG * 2);
  ushort* PWH  = (ushort*)alloc((size_t)PWN * 2);
  ushort* PWL  = (ushort*)alloc((size_t)PWN * 2);
  ushort* PUH  = (ushort*)alloc((size_t)PUN * 2);
  ushort* PUL  = (ushort*)alloc((size_t)PUN * 2);
  float*  h0   = (float*) alloc((size_t)HPAD * SIZE * 4);
  float*  h1   = (float*) alloc((size_t)HPAD * SIZE * 4);

  k_zero <<<2048, 256, 0, stream>>>(deg, (uint32_t*)adj, h0 + ND, h1 + ND);
  k_build<<<NE*N_NOTES, 256, 0, stream>>>((const float4v*)edge, deg, adj);
  k_pack <<<(PWN + PUN)/256, 256, 0, stream>>>(wz, wr, wh, uz, ur, uh, PWH, PWL, PUH, PUL);
  hipMemcpyAsync(h0, x, ND*4, hipMemcpyDeviceToDevice, stream);

  float* hcur = h0;
  float* hnxt = h1;
  for (int it = 0; it < NITER; ++it){
    k_fused<<<N_NOTES/16, 1024, 0, stream>>>(deg, adj, PWH, PWL, PUH, PUL,
                                             bz, br, bh, hcur, hnxt,
                                             out, (it == NITER-1) ? 1 : 0);
    float* t = hcur; hcur = hnxt; hnxt = t;
  }
}